// Round 4
// baseline (147.178 us; speedup 1.0000x reference)
//
#include <hip/hip_runtime.h>
#include <hip/hip_bf16.h>
#include <cstdint>

typedef unsigned short u16;
typedef __attribute__((ext_vector_type(8))) short bf16x8;
typedef __attribute__((ext_vector_type(4))) float f32x4;

#define NB 64
#define NN 197
#define NC 768
#define NH 12
#define ND 64
#define NM (NB*NN)   // 12608
#define CAP 96       // max selected tokens per batch (mean ~26, 15-sigma safe)
#define ASZ ((size_t)NM*NC)
#define WSZ ((size_t)NC*NC)
#define SELSZ ((size_t)NB*CAP*NC)

__device__ __forceinline__ u16 f2bf(float f) {
  uint32_t u = __float_as_uint(f);
  u += 0x7fffu + ((u >> 16) & 1u);
  return (u16)(u >> 16);
}

__device__ __forceinline__ void gl_lds16(const u16* g, u16* l) {
  __builtin_amdgcn_global_load_lds(
      (const __attribute__((address_space(1))) void*)g,
      (__attribute__((address_space(3))) void*)l, 16, 0, 0);
}

// ---------------- fp32 -> bf16 conversion, all 5 tensors, flat grid ---------
#define XBLK 9456   // ceil(ASZ/4/256)
#define WBLK 576    // WSZ/4/256
__global__ __launch_bounds__(256) void cvt_all(const float* __restrict__ x,
    const float* __restrict__ wq, const float* __restrict__ wk,
    const float* __restrict__ wv, const float* __restrict__ wp,
    u16* __restrict__ xb, u16* __restrict__ wqb, u16* __restrict__ wkb,
    u16* __restrict__ wvb, u16* __restrict__ wpb) {
  int bid = blockIdx.x;
  const float* src; u16* dst; int n4; int i;
  if (bid < XBLK) {
    src = x; dst = xb; n4 = (int)(ASZ/4); i = bid * 256 + threadIdx.x;
  } else {
    int t = bid - XBLK;
    int seg = t / WBLK;
    i = (t - seg * WBLK) * 256 + threadIdx.x;
    n4 = (int)(WSZ/4);
    if (seg == 0)      { src = wq; dst = wqb; }
    else if (seg == 1) { src = wk; dst = wkb; }
    else if (seg == 2) { src = wv; dst = wvb; }
    else               { src = wp; dst = wpb; }
  }
  if (i >= n4) return;
  float4 f = ((const float4*)src)[i];
  ushort4 o;
  o.x = f2bf(f.x); o.y = f2bf(f.y); o.z = f2bf(f.z); o.w = f2bf(f.w);
  ((ushort4*)dst)[i] = o;
}

// ---------------- transpose Wv (f32) -> WvT (bf16): WvT[k][j] = Wv[j][k] ----
__global__ __launch_bounds__(256) void trans_wv(const float* __restrict__ wv,
                                                u16* __restrict__ wvt) {
  __shared__ u16 T[64][72];
  int bx = blockIdx.x % 12, by = blockIdx.x / 12;
  int j0 = by * 64, k0 = bx * 64;
  int tid = threadIdx.x;
  #pragma unroll
  for (int g = 0; g < 4; ++g) {
    int r = g * 16 + (tid >> 4);       // j index 0..63
    int c4 = (tid & 15) * 4;           // k index 0..60
    float4 f = *(const float4*)(wv + (size_t)(j0 + r) * NC + k0 + c4);
    T[c4 + 0][r] = f2bf(f.x);
    T[c4 + 1][r] = f2bf(f.y);
    T[c4 + 2][r] = f2bf(f.z);
    T[c4 + 3][r] = f2bf(f.w);
  }
  __syncthreads();
  #pragma unroll
  for (int g = 0; g < 4; ++g) {
    int r = g * 16 + (tid >> 4);       // k index
    int c4 = (tid & 15) * 4;           // j index
    ushort4 o = *(ushort4*)&T[r][c4];
    *(ushort4*)(wvt + (size_t)(k0 + r) * NC + j0 + c4) = o;
  }
}

// ---------------- token gate: ts[b*197+n] in {0,1} --------------------------
__global__ __launch_bounds__(256) void gate_kernel(const float* __restrict__ x,
    const float* __restrict__ g1, const float* __restrict__ g2,
    const float* __restrict__ Wm, const float* __restrict__ bm,
    float* __restrict__ ts) {
  int wave = threadIdx.x >> 6;
  int lane = threadIdx.x & 63;
  int wid = blockIdx.x * 4 + wave;
  if (wid >= NM) return;
  int b = wid / NN, n = wid % NN;
  float out = 1.0f;
  if (n != 0) {
    const float* xr = x + (size_t)wid * NC;
    double acc = 0.0;
    #pragma unroll
    for (int i = 0; i < 12; ++i)
      acc += (double)xr[lane + 64*i] * (double)Wm[lane + 64*i];
    #pragma unroll
    for (int off = 32; off; off >>= 1) acc += __shfl_down(acc, off);
    double z = (acc + (double)bm[0] + (double)g1[b*(NN-1) + n - 1]
                                    - (double)g2[b*(NN-1) + n - 1]) / 5.0;
    // sigmoid(z) > 0.6  <=>  z > ln(1.5)
    out = (z > 0.4054651081081643820) ? 1.0f : 0.0f;
    out = __shfl(out, 0);
  }
  if (lane == 0) ts[wid] = out;
}

// ---------------- compact: build per-b ordered selected-token lists ---------
__global__ __launch_bounds__(256) void compact_kernel(const float* __restrict__ ts,
    int* __restrict__ idx, int* __restrict__ cnt) {
  __shared__ unsigned long long bmask[4];
  int b = blockIdx.x;
  int t = threadIdx.x, lane = t & 63, wave = t >> 6;
  bool sel = (t < NN) && (ts[b * NN + t] > 0.5f);
  unsigned long long m = __ballot(sel);
  if (lane == 0) bmask[wave] = m;
  __syncthreads();
  int before = 0;
  #pragma unroll
  for (int w = 0; w < 4; ++w) if (w < wave) before += __popcll(bmask[w]);
  int within = __popcll(bmask[wave] & ((lane == 0) ? 0ull : (~0ull >> (64 - lane))));
  int pos = before + within;
  int total = 0;
  #pragma unroll
  for (int w = 0; w < 4; ++w) total += __popcll(bmask[w]);
  int cntc = total < CAP ? total : CAP;
  if (sel && pos < CAP) idx[b * CAP + pos] = t;
  if (t == 0) cnt[b] = cntc;
  for (int i = cntc + t; i < CAP; i += 256) idx[b * CAP + i] = 0;
}

// ---------------- compacted Q/K/V projection: 32x128 tiles, gathered rows ---
// grid: x = b*3 + rowchunk, y = col tile (6), z = 0/1/2 (Q/K/V)
__global__ __launch_bounds__(256) void gemm_sel(const u16* __restrict__ xb,
    const u16* __restrict__ Wbase, u16* __restrict__ obase,
    const int* __restrict__ idx, const int* __restrict__ cnt) {
  alignas(16) __shared__ u16 As[32][32];
  alignas(16) __shared__ u16 Bs[128][32];
  int bx = blockIdx.x;
  int b = bx / 3, rc = bx % 3;
  int cntb = cnt[b];
  if (rc * 32 >= cntb) return;
  int z = blockIdx.z;
  const u16* W = Wbase + (size_t)z * WSZ;
  u16* o = obase + (size_t)z * SELSZ;
  int n0 = blockIdx.y * 128;
  int tid = threadIdx.x, lane = tid & 63, wave = tid >> 6;

  int chA = wave * 64 + lane;
  int tokA = idx[b * CAP + rc * 32 + (chA >> 2)];
  const u16* baseA = xb + (size_t)(b * NN + tokA) * NC + (chA & 3) * 8;
  u16* ldsA = &As[0][0] + (size_t)(wave * 64) * 8;
  int chB0 = wave * 64 + lane, chB1 = 256 + wave * 64 + lane;
  const u16* baseB0 = W + (size_t)(n0 + (chB0 >> 2)) * NC + (chB0 & 3) * 8;
  const u16* baseB1 = W + (size_t)(n0 + (chB1 >> 2)) * NC + (chB1 & 3) * 8;
  u16* ldsB0 = &Bs[0][0] + (size_t)(wave * 64) * 8;
  u16* ldsB1 = &Bs[0][0] + (size_t)(256 + wave * 64) * 8;

  int lr = lane & 15, lg = lane >> 4, lk = lg * 8;
  int wc = wave * 32;
  f32x4 acc[2][2];
  #pragma unroll
  for (int i = 0; i < 2; ++i)
    #pragma unroll
    for (int j = 0; j < 2; ++j) acc[i][j] = (f32x4){0.f,0.f,0.f,0.f};

  for (int k0 = 0; k0 < NC; k0 += 32) {
    if (wave < 2) gl_lds16(baseA + k0, ldsA);
    gl_lds16(baseB0 + k0, ldsB0);
    gl_lds16(baseB1 + k0, ldsB1);
    __syncthreads();
    bf16x8 af[2], bfr[2];
    #pragma unroll
    for (int f = 0; f < 2; ++f) {
      af[f]  = *(const bf16x8*)(&As[f*16 + lr][lk]);
      bfr[f] = *(const bf16x8*)(&Bs[wc + f*16 + lr][lk]);
    }
    #pragma unroll
    for (int i = 0; i < 2; ++i)
      #pragma unroll
      for (int j = 0; j < 2; ++j)
        acc[i][j] = __builtin_amdgcn_mfma_f32_16x16x32_bf16(af[i], bfr[j], acc[i][j], 0, 0, 0);
    __syncthreads();
  }

  #pragma unroll
  for (int i = 0; i < 2; ++i)
    #pragma unroll
    for (int j = 0; j < 2; ++j)
      #pragma unroll
      for (int r = 0; r < 4; ++r) {
        int rsel = rc*32 + i*16 + 4*lg + r;
        if (rsel < cntb)
          o[(size_t)(b * CAP + rsel) * NC + n0 + wc + j*16 + lr] = f2bf(acc[i][j][r]);
      }
}

// ---------------- sparse attention over selected tokens per (b,h) -----------
__global__ __launch_bounds__(256) void attn_sel(const u16* __restrict__ qsel,
    const u16* __restrict__ ksel, const u16* __restrict__ vsel,
    u16* __restrict__ zsel, const int* __restrict__ cnt) {
  alignas(16) __shared__ u16 Vt[64][232];
  int bh = blockIdx.x;
  int b = bh / NH, h = bh % NH;
  int cntb = cnt[b];
  int tid = threadIdx.x, lane = tid & 63, wave = tid >> 6;
  int lr = lane & 15, lg = lane >> 4;
  const size_t qbase = (size_t)b * CAP * NC + (size_t)h * ND;

  // stage V^T from compacted vsel
  for (int id = tid; id < cntb * 8; id += 256) {
    int i = id >> 3, c8 = (id & 7) * 8;
    int4 val = *(const int4*)(vsel + qbase + (size_t)i * NC + c8);
    u16 tmp[8];
    *(int4*)tmp = val;
    #pragma unroll
    for (int e = 0; e < 8; ++e) Vt[c8 + e][i] = tmp[e];
  }
  for (int id = tid; id < 64 * 32; id += 256)
    Vt[id >> 5][cntb + (id & 31)] = 0;
  __syncthreads();

  int nchunk = (cntb + 15) >> 4;
  int mtmax  = nchunk;
  int mcmax  = (cntb + 31) >> 5;
  int idx0 = (((lane & 15) | ((lane & 16) << 1))) << 2;  // (lr + 32*(lg&1))*4
  int idx1 = idx0 + 64;

  for (int qc = wave; qc < nchunk; qc += 4) {
    const u16* qp = qsel + qbase + (size_t)(qc * 16 + lr) * NC + lg * 8;
    bf16x8 qf0 = *(const bf16x8*)(qp);
    bf16x8 qf1 = *(const bf16x8*)(qp + 32);

    f32x4 s[6];
    #pragma unroll
    for (int mt = 0; mt < 6; ++mt) s[mt] = (f32x4){0.f,0.f,0.f,0.f};
    #pragma unroll
    for (int mt = 0; mt < 6; ++mt) {
      if (mt < mtmax) {
        const u16* kp = ksel + qbase + (size_t)(mt * 16 + lr) * NC + lg * 8;
        bf16x8 kf0 = *(const bf16x8*)(kp);
        bf16x8 kf1 = *(const bf16x8*)(kp + 32);
        f32x4 a = (f32x4){0.f,0.f,0.f,0.f};
        a = __builtin_amdgcn_mfma_f32_16x16x32_bf16(kf0, qf0, a, 0, 0, 0);
        a = __builtin_amdgcn_mfma_f32_16x16x32_bf16(kf1, qf1, a, 0, 0, 0);
        s[mt] = a;
      }
    }

    float mx = -3e38f;
    #pragma unroll
    for (int mt = 0; mt < 6; ++mt)
      #pragma unroll
      for (int jj = 0; jj < 4; ++jj) {
        int m = mt*16 + 4*lg + jj;
        float val = (m < cntb) ? s[mt][jj] * 0.125f : -1e30f;
        s[mt][jj] = val;
        mx = fmaxf(mx, val);
      }
    mx = fmaxf(mx, __shfl_xor(mx, 16));
    mx = fmaxf(mx, __shfl_xor(mx, 32));
    float sum = 0.f;
    #pragma unroll
    for (int mt = 0; mt < 6; ++mt)
      #pragma unroll
      for (int jj = 0; jj < 4; ++jj) {
        float p = __expf(s[mt][jj] - mx);
        s[mt][jj] = p;
        sum += p;
      }
    sum += __shfl_xor(sum, 16);
    sum += __shfl_xor(sum, 32);
    float inv = 1.0f / sum;

    uint32_t u[6][2];
    #pragma unroll
    for (int mt = 0; mt < 6; ++mt) {
      u[mt][0] = ((uint32_t)f2bf(s[mt][1]*inv) << 16) | f2bf(s[mt][0]*inv);
      u[mt][1] = ((uint32_t)f2bf(s[mt][3]*inv) << 16) | f2bf(s[mt][2]*inv);
    }

    f32x4 oacc[4];
    #pragma unroll
    for (int dt = 0; dt < 4; ++dt) oacc[dt] = (f32x4){0.f,0.f,0.f,0.f};
    #pragma unroll
    for (int mc = 0; mc < 3; ++mc) {
      if (mc < mcmax) {
        uint32_t a0 = (uint32_t)__builtin_amdgcn_ds_bpermute(idx0, (int)u[2*mc][0]);
        uint32_t b0 = (uint32_t)__builtin_amdgcn_ds_bpermute(idx0, (int)u[2*mc+1][0]);
        uint32_t a1 = (uint32_t)__builtin_amdgcn_ds_bpermute(idx0, (int)u[2*mc][1]);
        uint32_t b1 = (uint32_t)__builtin_amdgcn_ds_bpermute(idx0, (int)u[2*mc+1][1]);
        uint32_t a2 = (uint32_t)__builtin_amdgcn_ds_bpermute(idx1, (int)u[2*mc][0]);
        uint32_t b2 = (uint32_t)__builtin_amdgcn_ds_bpermute(idx1, (int)u[2*mc+1][0]);
        uint32_t a3 = (uint32_t)__builtin_amdgcn_ds_bpermute(idx1, (int)u[2*mc][1]);
        uint32_t b3 = (uint32_t)__builtin_amdgcn_ds_bpermute(idx1, (int)u[2*mc+1][1]);
        bool hi = (lg >= 2);
        union { uint32_t w[4]; bf16x8 v; } pu;
        pu.w[0] = hi ? b0 : a0;
        pu.w[1] = hi ? b1 : a1;
        pu.w[2] = hi ? b2 : a2;
        pu.w[3] = hi ? b3 : a3;
        bf16x8 pa = pu.v;
        #pragma unroll
        for (int dt = 0; dt < 4; ++dt) {
          bf16x8 vf = *(const bf16x8*)(&Vt[dt*16 + lr][mc*32 + lg*8]);
          oacc[dt] = __builtin_amdgcn_mfma_f32_16x16x32_bf16(pa, vf, oacc[dt], 0, 0, 0);
        }
      }
    }

    // store compact: zsel[b*CAP + n][h*ND + d]
    #pragma unroll
    for (int r = 0; r < 4; ++r) {
      int nloc = qc*16 + 4*lg + r;
      if (nloc < cntb) {
        u16* op = zsel + qbase + (size_t)nloc * NC + lr;
        #pragma unroll
        for (int dt = 0; dt < 4; ++dt)
          op[dt*16] = f2bf(oacc[dt][r]);
      }
    }
  }
}

// ---------------- proj for selected rows: out[tok] = zsel @ Wp^T + bp -------
// grid: x = b*3 + rowchunk, y = col tile (6). f32 scatter into dense output.
__global__ __launch_bounds__(256) void proj_sel(const u16* __restrict__ zsel,
    const u16* __restrict__ wpb, float* __restrict__ out,
    const float* __restrict__ bp, const int* __restrict__ idx,
    const int* __restrict__ cnt) {
  alignas(16) __shared__ u16 As[32][32];
  alignas(16) __shared__ u16 Bs[128][32];
  int bx = blockIdx.x;
  int b = bx / 3, rc = bx % 3;
  int cntb = cnt[b];
  if (rc * 32 >= cntb) return;
  int n0 = blockIdx.y * 128;
  int tid = threadIdx.x, lane = tid & 63, wave = tid >> 6;

  int chA = wave * 64 + lane;
  const u16* baseA = zsel + (size_t)(b * CAP + rc * 32 + (chA >> 2)) * NC + (chA & 3) * 8;
  u16* ldsA = &As[0][0] + (size_t)(wave * 64) * 8;
  int chB0 = wave * 64 + lane, chB1 = 256 + wave * 64 + lane;
  const u16* baseB0 = wpb + (size_t)(n0 + (chB0 >> 2)) * NC + (chB0 & 3) * 8;
  const u16* baseB1 = wpb + (size_t)(n0 + (chB1 >> 2)) * NC + (chB1 & 3) * 8;
  u16* ldsB0 = &Bs[0][0] + (size_t)(wave * 64) * 8;
  u16* ldsB1 = &Bs[0][0] + (size_t)(256 + wave * 64) * 8;

  int lr = lane & 15, lg = lane >> 4, lk = lg * 8;
  int wc = wave * 32;
  f32x4 acc[2][2];
  #pragma unroll
  for (int i = 0; i < 2; ++i)
    #pragma unroll
    for (int j = 0; j < 2; ++j) acc[i][j] = (f32x4){0.f,0.f,0.f,0.f};

  for (int k0 = 0; k0 < NC; k0 += 32) {
    if (wave < 2) gl_lds16(baseA + k0, ldsA);
    gl_lds16(baseB0 + k0, ldsB0);
    gl_lds16(baseB1 + k0, ldsB1);
    __syncthreads();
    bf16x8 af[2], bfr[2];
    #pragma unroll
    for (int f = 0; f < 2; ++f) {
      af[f]  = *(const bf16x8*)(&As[f*16 + lr][lk]);
      bfr[f] = *(const bf16x8*)(&Bs[wc + f*16 + lr][lk]);
    }
    #pragma unroll
    for (int i = 0; i < 2; ++i)
      #pragma unroll
      for (int j = 0; j < 2; ++j)
        acc[i][j] = __builtin_amdgcn_mfma_f32_16x16x32_bf16(af[i], bfr[j], acc[i][j], 0, 0, 0);
    __syncthreads();
  }

  #pragma unroll
  for (int i = 0; i < 2; ++i)
    #pragma unroll
    for (int j = 0; j < 2; ++j)
      #pragma unroll
      for (int r = 0; r < 4; ++r) {
        int rsel = rc*32 + i*16 + 4*lg + r;
        if (rsel < cntb) {
          int tok = idx[b * CAP + rsel];
          int col = n0 + wc + j*16 + lr;
          out[(size_t)(b * NN + tok) * NC + col] = acc[i][j][r] + bp[col];
        }
      }
}

// ---------------- dense NT GEMM, BK=64, XOR-swizzled LDS, XCD-chunked -------
// out[m][n] = sum_k A[m][k]*W[n][k]. 128x128 tile, 1-D grid nmt*nnt,
// n-fastest tile order so consecutive blocks (same XCD chunk) share A-panel.
template<int F32OUT>
__global__ __launch_bounds__(256) void gemm_nt(const u16* __restrict__ A,
                                               const u16* __restrict__ W,
                                               u16* __restrict__ obf,
                                               float* __restrict__ of32,
                                               const float* __restrict__ bias,
                                               int M, int nnt) {
  alignas(16) __shared__ u16 As[128][64];
  alignas(16) __shared__ u16 Bs[128][64];
  int nwg = gridDim.x;
  int orig = blockIdx.x;
  int q8 = nwg >> 3, r8 = nwg & 7;
  int xcd = orig & 7, loc = orig >> 3;
  int wgid = (xcd < r8 ? xcd * (q8 + 1) : r8 * (q8 + 1) + (xcd - r8) * q8) + loc;
  int m0 = (wgid / nnt) * 128;
  int n0 = (wgid % nnt) * 128;
  int tid = threadIdx.x;
  int lane = tid & 63, wave = tid >> 6;
  int wr = (wave >> 1) * 64, wc = (wave & 1) * 64;
  int lr = lane & 15, lg = lane >> 4, r7 = lr & 7;
  // staging: id = c*64+lane; row = id>>3 = c*8+(lane>>3); slot = lane&7
  // source col pre-swizzled: (slot ^ (row&7))*8 ; LDS dest linear
  int colsw = ((lane & 7) ^ (lane >> 3)) * 8;
  int rowl = lane >> 3;

  f32x4 acc[4][4];
  #pragma unroll
  for (int i = 0; i < 4; ++i)
    #pragma unroll
    for (int j = 0; j < 4; ++j)
      acc[i][j] = (f32x4){0.f, 0.f, 0.f, 0.f};

  int s0 = (lg ^ r7) * 8;
  int s1 = ((4 + lg) ^ r7) * 8;

  for (int k0 = 0; k0 < NC; k0 += 64) {
    #pragma unroll
    for (int i = 0; i < 4; ++i) {
      int c = wave * 4 + i;
      int row = c * 8 + rowl;
      gl_lds16(A + (size_t)(m0 + row) * NC + k0 + colsw, &As[0][0] + c * 512);
      gl_lds16(W + (size_t)(n0 + row) * NC + k0 + colsw, &Bs[0][0] + c * 512);
    }
    __syncthreads();
    bf16x8 a0[4], a1[4], b0[4], b1[4];
    #pragma unroll
    for (int f = 0; f < 4; ++f) {
      int ra = wr + f*16 + lr;
      int rb = wc + f*16 + lr;
      a0[f] = *(const bf16x8*)(&As[ra][s0]);
      a1[f] = *(const bf16x8*)(&As[ra][s1]);
      b0[f] = *(const bf16x8*)(&Bs[rb][s0]);
      b1[f] = *(const bf16x8*)(&Bs[rb][s1]);
    }
    #pragma unroll
    for (int i = 0; i < 4; ++i)
      #pragma unroll
      for (int j = 0; j < 4; ++j)
        acc[i][j] = __builtin_amdgcn_mfma_f32_16x16x32_bf16(a0[i], b0[j], acc[i][j], 0, 0, 0);
    #pragma unroll
    for (int i = 0; i < 4; ++i)
      #pragma unroll
      for (int j = 0; j < 4; ++j)
        acc[i][j] = __builtin_amdgcn_mfma_f32_16x16x32_bf16(a1[i], b1[j], acc[i][j], 0, 0, 0);
    __syncthreads();
  }

  #pragma unroll
  for (int i = 0; i < 4; ++i) {
    int rbase = m0 + wr + i*16 + 4*lg;
    #pragma unroll
    for (int j = 0; j < 4; ++j) {
      int col = n0 + wc + j*16 + lr;
      #pragma unroll
      for (int r = 0; r < 4; ++r) {
        int row = rbase + r;
        if (row < M) {
          if (F32OUT) of32[(size_t)row * NC + col] = acc[i][j][r] + bias[col];
          else        obf[(size_t)row * NC + col] = f2bf(acc[i][j][r]);
        }
      }
    }
  }
}

// ---------------------------------------------------------------------------
extern "C" void kernel_launch(void* const* d_in, const int* in_sizes, int n_in,
                              void* d_out, int out_size, void* d_ws, size_t ws_size,
                              hipStream_t stream) {
  const float* x  = (const float*)d_in[0];
  const float* g1 = (const float*)d_in[1];
  const float* g2 = (const float*)d_in[2];
  const float* Wq = (const float*)d_in[3];
  const float* Wk = (const float*)d_in[4];
  const float* Wv = (const float*)d_in[5];
  const float* Wp = (const float*)d_in[6];
  const float* bp = (const float*)d_in[7];
  const float* Wm = (const float*)d_in[8];
  const float* bm = (const float*)d_in[9];
  float* out = (float*)d_out;

  const size_t act_sz = ASZ * 2;
  const size_t w_sz   = WSZ * 2;
  const size_t sel_sz = SELSZ * 2;
  size_t need = act_sz + 4*sel_sz + 6*w_sz + (size_t)NM*4 + (size_t)NB*CAP*4 + 256;
  if (ws_size < need) return;

  char* p = (char*)d_ws;
  u16* xb   = (u16*)p; p += act_sz;
  u16* qsel = (u16*)p; p += sel_sz;    // qsel,ksel,vsel consecutive (z*SELSZ)
  u16* ksel = (u16*)p; p += sel_sz;
  u16* vsel = (u16*)p; p += sel_sz;
  u16* zsel = (u16*)p; p += sel_sz;
  u16* wqb  = (u16*)p; p += w_sz;      // wqb,wkb,wvb consecutive (z*WSZ)
  u16* wkb  = (u16*)p; p += w_sz;
  u16* wvb  = (u16*)p; p += w_sz;
  u16* wpb  = (u16*)p; p += w_sz;
  u16* wvtb = (u16*)p; p += w_sz;      // Wv^T bf16
  u16* wvpb = (u16*)p; p += w_sz;      // Wvp = Wp @ Wv (row i, col k layout)
  float* ts = (float*)p; p += (size_t)NM*4;
  int* idx  = (int*)p;  p += (size_t)NB*CAP*4;
  int* cnt  = (int*)p;
  (void)ksel; (void)vsel; (void)wkb; (void)wvb;

  // 1. conversions + Wv transpose
  cvt_all<<<dim3(XBLK + 4*WBLK), 256, 0, stream>>>(
      x, Wq, Wk, Wv, Wp, xb, wqb, wkb, wvb, wpb);
  trans_wv<<<dim3(144), 256, 0, stream>>>(Wv, wvtb);

  // 2. gates + compact
  gate_kernel<<<dim3(NM/4), 256, 0, stream>>>(x, g1, g2, Wm, bm, ts);
  compact_kernel<<<dim3(NB), 256, 0, stream>>>(ts, idx, cnt);

  // 3. Wvp = Wp @ Wv  (as NT: Wvp[i][k] = sum_j Wpb[i][j] * WvT[k][j])
  gemm_nt<0><<<dim3(36), 256, 0, stream>>>(wpb, wvtb, wvpb, nullptr, nullptr, NC, 6);

  // 4. Q/K/V projections for selected rows only
  gemm_sel<<<dim3(NB*3, 6, 3), 256, 0, stream>>>(xb, wqb, qsel, idx, cnt);

  // 5. sparse attention -> compacted zsel
  attn_sel<<<dim3(NB*NH), 256, 0, stream>>>(qsel, ksel, vsel, zsel, cnt);

  // 6. dense fused GEMM: out = x @ Wvp^T + bp (default/unselected path)
  gemm_nt<1><<<dim3(99*6), 256, 0, stream>>>(xb, wvpb, nullptr, out, bp, NM, 6);

  // 7. overwrite selected rows: out[tok] = zsel @ Wp^T + bp
  proj_sel<<<dim3(NB*3, 6), 256, 0, stream>>>(zsel, wpb, out, bp, idx, cnt);
}

// Round 5
// 135.620 us; speedup vs baseline: 1.0852x; 1.0852x over previous
//
#include <hip/hip_runtime.h>
#include <hip/hip_bf16.h>
#include <cstdint>

typedef unsigned short u16;
typedef __attribute__((ext_vector_type(8))) short bf16x8;
typedef __attribute__((ext_vector_type(4))) float f32x4;

#define NB 64
#define NN 197
#define NC 768
#define NH 12
#define ND 64
#define NM (NB*NN)   // 12608
#define CAP 96       // max selected tokens per batch (mean ~26, 15-sigma safe)
#define ASZ ((size_t)NM*NC)
#define WSZ ((size_t)NC*NC)
#define SELSZ ((size_t)NB*CAP*NC)

__device__ __forceinline__ u16 f2bf(float f) {
  uint32_t u = __float_as_uint(f);
  u += 0x7fffu + ((u >> 16) & 1u);
  return (u16)(u >> 16);
}

__device__ __forceinline__ void gl_lds16(const u16* g, u16* l) {
  __builtin_amdgcn_global_load_lds(
      (const __attribute__((address_space(1))) void*)g,
      (__attribute__((address_space(3))) void*)l, 16, 0, 0);
}

// ---------------- fp32 -> bf16 conversion, all 5 tensors, flat grid ---------
#define XBLK 9456   // ceil(ASZ/4/256)
#define WBLK 576    // WSZ/4/256
__global__ __launch_bounds__(256) void cvt_all(const float* __restrict__ x,
    const float* __restrict__ wq, const float* __restrict__ wk,
    const float* __restrict__ wv, const float* __restrict__ wp,
    u16* __restrict__ xb, u16* __restrict__ wqb, u16* __restrict__ wkb,
    u16* __restrict__ wvb, u16* __restrict__ wpb) {
  int bid = blockIdx.x;
  const float* src; u16* dst; int n4; int i;
  if (bid < XBLK) {
    src = x; dst = xb; n4 = (int)(ASZ/4); i = bid * 256 + threadIdx.x;
  } else {
    int t = bid - XBLK;
    int seg = t / WBLK;
    i = (t - seg * WBLK) * 256 + threadIdx.x;
    n4 = (int)(WSZ/4);
    if (seg == 0)      { src = wq; dst = wqb; }
    else if (seg == 1) { src = wk; dst = wkb; }
    else if (seg == 2) { src = wv; dst = wvb; }
    else               { src = wp; dst = wpb; }
  }
  if (i >= n4) return;
  float4 f = ((const float4*)src)[i];
  ushort4 o;
  o.x = f2bf(f.x); o.y = f2bf(f.y); o.z = f2bf(f.z); o.w = f2bf(f.w);
  ((ushort4*)dst)[i] = o;
}

// ---------------- transpose Wv (f32) -> WvT (bf16): WvT[k][j] = Wv[j][k] ----
__global__ __launch_bounds__(256) void trans_wv(const float* __restrict__ wv,
                                                u16* __restrict__ wvt) {
  __shared__ u16 T[64][72];
  int bx = blockIdx.x % 12, by = blockIdx.x / 12;
  int j0 = by * 64, k0 = bx * 64;
  int tid = threadIdx.x;
  #pragma unroll
  for (int g = 0; g < 4; ++g) {
    int r = g * 16 + (tid >> 4);       // j index 0..63
    int c4 = (tid & 15) * 4;           // k index 0..60
    float4 f = *(const float4*)(wv + (size_t)(j0 + r) * NC + k0 + c4);
    T[c4 + 0][r] = f2bf(f.x);
    T[c4 + 1][r] = f2bf(f.y);
    T[c4 + 2][r] = f2bf(f.z);
    T[c4 + 3][r] = f2bf(f.w);
  }
  __syncthreads();
  #pragma unroll
  for (int g = 0; g < 4; ++g) {
    int r = g * 16 + (tid >> 4);       // k index
    int c4 = (tid & 15) * 4;           // j index
    ushort4 o = *(ushort4*)&T[r][c4];
    *(ushort4*)(wvt + (size_t)(k0 + r) * NC + j0 + c4) = o;
  }
}

// ---------------- token gate: ts[b*197+n] in {0,1} --------------------------
__global__ __launch_bounds__(256) void gate_kernel(const float* __restrict__ x,
    const float* __restrict__ g1, const float* __restrict__ g2,
    const float* __restrict__ Wm, const float* __restrict__ bm,
    float* __restrict__ ts) {
  int wave = threadIdx.x >> 6;
  int lane = threadIdx.x & 63;
  int wid = blockIdx.x * 4 + wave;
  if (wid >= NM) return;
  int b = wid / NN, n = wid % NN;
  float out = 1.0f;
  if (n != 0) {
    const float* xr = x + (size_t)wid * NC;
    double acc = 0.0;
    #pragma unroll
    for (int i = 0; i < 12; ++i)
      acc += (double)xr[lane + 64*i] * (double)Wm[lane + 64*i];
    #pragma unroll
    for (int off = 32; off; off >>= 1) acc += __shfl_down(acc, off);
    double z = (acc + (double)bm[0] + (double)g1[b*(NN-1) + n - 1]
                                    - (double)g2[b*(NN-1) + n - 1]) / 5.0;
    // sigmoid(z) > 0.6  <=>  z > ln(1.5)
    out = (z > 0.4054651081081643820) ? 1.0f : 0.0f;
    out = __shfl(out, 0);
  }
  if (lane == 0) ts[wid] = out;
}

// ---------------- compact: build per-b ordered selected-token lists ---------
__global__ __launch_bounds__(256) void compact_kernel(const float* __restrict__ ts,
    int* __restrict__ idx, int* __restrict__ cnt) {
  __shared__ unsigned long long bmask[4];
  int b = blockIdx.x;
  int t = threadIdx.x, lane = t & 63, wave = t >> 6;
  bool sel = (t < NN) && (ts[b * NN + t] > 0.5f);
  unsigned long long m = __ballot(sel);
  if (lane == 0) bmask[wave] = m;
  __syncthreads();
  int before = 0;
  #pragma unroll
  for (int w = 0; w < 4; ++w) if (w < wave) before += __popcll(bmask[w]);
  int within = __popcll(bmask[wave] & ((lane == 0) ? 0ull : (~0ull >> (64 - lane))));
  int pos = before + within;
  int total = 0;
  #pragma unroll
  for (int w = 0; w < 4; ++w) total += __popcll(bmask[w]);
  int cntc = total < CAP ? total : CAP;
  if (sel && pos < CAP) idx[b * CAP + pos] = t;
  if (t == 0) cnt[b] = cntc;
  for (int i = cntc + t; i < CAP; i += 256) idx[b * CAP + i] = 0;
}

// ---------------- compacted Q/K/V projection: 32x128 tiles, gathered rows ---
// grid: x = b*3 + rowchunk, y = col tile (6), z = 0/1/2 (Q/K/V)
__global__ __launch_bounds__(256) void gemm_sel(const u16* __restrict__ xb,
    const u16* __restrict__ Wbase, u16* __restrict__ obase,
    const int* __restrict__ idx, const int* __restrict__ cnt) {
  alignas(16) __shared__ u16 As[32][32];
  alignas(16) __shared__ u16 Bs[128][32];
  int bx = blockIdx.x;
  int b = bx / 3, rc = bx % 3;
  int cntb = cnt[b];
  if (rc * 32 >= cntb) return;
  int z = blockIdx.z;
  const u16* W = Wbase + (size_t)z * WSZ;
  u16* o = obase + (size_t)z * SELSZ;
  int n0 = blockIdx.y * 128;
  int tid = threadIdx.x, lane = tid & 63, wave = tid >> 6;

  int chA = wave * 64 + lane;
  int tokA = idx[b * CAP + rc * 32 + (chA >> 2)];
  const u16* baseA = xb + (size_t)(b * NN + tokA) * NC + (chA & 3) * 8;
  u16* ldsA = &As[0][0] + (size_t)(wave * 64) * 8;
  int chB0 = wave * 64 + lane, chB1 = 256 + wave * 64 + lane;
  const u16* baseB0 = W + (size_t)(n0 + (chB0 >> 2)) * NC + (chB0 & 3) * 8;
  const u16* baseB1 = W + (size_t)(n0 + (chB1 >> 2)) * NC + (chB1 & 3) * 8;
  u16* ldsB0 = &Bs[0][0] + (size_t)(wave * 64) * 8;
  u16* ldsB1 = &Bs[0][0] + (size_t)(256 + wave * 64) * 8;

  int lr = lane & 15, lg = lane >> 4, lk = lg * 8;
  int wc = wave * 32;
  f32x4 acc[2][2];
  #pragma unroll
  for (int i = 0; i < 2; ++i)
    #pragma unroll
    for (int j = 0; j < 2; ++j) acc[i][j] = (f32x4){0.f,0.f,0.f,0.f};

  for (int k0 = 0; k0 < NC; k0 += 32) {
    if (wave < 2) gl_lds16(baseA + k0, ldsA);
    gl_lds16(baseB0 + k0, ldsB0);
    gl_lds16(baseB1 + k0, ldsB1);
    __syncthreads();
    bf16x8 af[2], bfr[2];
    #pragma unroll
    for (int f = 0; f < 2; ++f) {
      af[f]  = *(const bf16x8*)(&As[f*16 + lr][lk]);
      bfr[f] = *(const bf16x8*)(&Bs[wc + f*16 + lr][lk]);
    }
    #pragma unroll
    for (int i = 0; i < 2; ++i)
      #pragma unroll
      for (int j = 0; j < 2; ++j)
        acc[i][j] = __builtin_amdgcn_mfma_f32_16x16x32_bf16(af[i], bfr[j], acc[i][j], 0, 0, 0);
    __syncthreads();
  }

  #pragma unroll
  for (int i = 0; i < 2; ++i)
    #pragma unroll
    for (int j = 0; j < 2; ++j)
      #pragma unroll
      for (int r = 0; r < 4; ++r) {
        int rsel = rc*32 + i*16 + 4*lg + r;
        if (rsel < cntb)
          o[(size_t)(b * CAP + rsel) * NC + n0 + wc + j*16 + lr] = f2bf(acc[i][j][r]);
      }
}

// ---------------- sparse attention over selected tokens per (b,h) -----------
__global__ __launch_bounds__(256) void attn_sel(const u16* __restrict__ qsel,
    const u16* __restrict__ ksel, const u16* __restrict__ vsel,
    u16* __restrict__ zsel, const int* __restrict__ cnt) {
  alignas(16) __shared__ u16 Vt[64][232];
  int bh = blockIdx.x;
  int b = bh / NH, h = bh % NH;
  int cntb = cnt[b];
  int tid = threadIdx.x, lane = tid & 63, wave = tid >> 6;
  int lr = lane & 15, lg = lane >> 4;
  const size_t qbase = (size_t)b * CAP * NC + (size_t)h * ND;

  // stage V^T from compacted vsel
  for (int id = tid; id < cntb * 8; id += 256) {
    int i = id >> 3, c8 = (id & 7) * 8;
    int4 val = *(const int4*)(vsel + qbase + (size_t)i * NC + c8);
    u16 tmp[8];
    *(int4*)tmp = val;
    #pragma unroll
    for (int e = 0; e < 8; ++e) Vt[c8 + e][i] = tmp[e];
  }
  for (int id = tid; id < 64 * 32; id += 256)
    Vt[id >> 5][cntb + (id & 31)] = 0;
  __syncthreads();

  int nchunk = (cntb + 15) >> 4;
  int mtmax  = nchunk;
  int mcmax  = (cntb + 31) >> 5;
  int idx0 = (((lane & 15) | ((lane & 16) << 1))) << 2;  // (lr + 32*(lg&1))*4
  int idx1 = idx0 + 64;

  for (int qc = wave; qc < nchunk; qc += 4) {
    const u16* qp = qsel + qbase + (size_t)(qc * 16 + lr) * NC + lg * 8;
    bf16x8 qf0 = *(const bf16x8*)(qp);
    bf16x8 qf1 = *(const bf16x8*)(qp + 32);

    f32x4 s[6];
    #pragma unroll
    for (int mt = 0; mt < 6; ++mt) s[mt] = (f32x4){0.f,0.f,0.f,0.f};
    #pragma unroll
    for (int mt = 0; mt < 6; ++mt) {
      if (mt < mtmax) {
        const u16* kp = ksel + qbase + (size_t)(mt * 16 + lr) * NC + lg * 8;
        bf16x8 kf0 = *(const bf16x8*)(kp);
        bf16x8 kf1 = *(const bf16x8*)(kp + 32);
        f32x4 a = (f32x4){0.f,0.f,0.f,0.f};
        a = __builtin_amdgcn_mfma_f32_16x16x32_bf16(kf0, qf0, a, 0, 0, 0);
        a = __builtin_amdgcn_mfma_f32_16x16x32_bf16(kf1, qf1, a, 0, 0, 0);
        s[mt] = a;
      }
    }

    float mx = -3e38f;
    #pragma unroll
    for (int mt = 0; mt < 6; ++mt)
      #pragma unroll
      for (int jj = 0; jj < 4; ++jj) {
        int m = mt*16 + 4*lg + jj;
        float val = (m < cntb) ? s[mt][jj] * 0.125f : -1e30f;
        s[mt][jj] = val;
        mx = fmaxf(mx, val);
      }
    mx = fmaxf(mx, __shfl_xor(mx, 16));
    mx = fmaxf(mx, __shfl_xor(mx, 32));
    float sum = 0.f;
    #pragma unroll
    for (int mt = 0; mt < 6; ++mt)
      #pragma unroll
      for (int jj = 0; jj < 4; ++jj) {
        float p = __expf(s[mt][jj] - mx);
        s[mt][jj] = p;
        sum += p;
      }
    sum += __shfl_xor(sum, 16);
    sum += __shfl_xor(sum, 32);
    float inv = 1.0f / sum;

    uint32_t u[6][2];
    #pragma unroll
    for (int mt = 0; mt < 6; ++mt) {
      u[mt][0] = ((uint32_t)f2bf(s[mt][1]*inv) << 16) | f2bf(s[mt][0]*inv);
      u[mt][1] = ((uint32_t)f2bf(s[mt][3]*inv) << 16) | f2bf(s[mt][2]*inv);
    }

    f32x4 oacc[4];
    #pragma unroll
    for (int dt = 0; dt < 4; ++dt) oacc[dt] = (f32x4){0.f,0.f,0.f,0.f};
    #pragma unroll
    for (int mc = 0; mc < 3; ++mc) {
      if (mc < mcmax) {
        uint32_t a0 = (uint32_t)__builtin_amdgcn_ds_bpermute(idx0, (int)u[2*mc][0]);
        uint32_t b0 = (uint32_t)__builtin_amdgcn_ds_bpermute(idx0, (int)u[2*mc+1][0]);
        uint32_t a1 = (uint32_t)__builtin_amdgcn_ds_bpermute(idx0, (int)u[2*mc][1]);
        uint32_t b1 = (uint32_t)__builtin_amdgcn_ds_bpermute(idx0, (int)u[2*mc+1][1]);
        uint32_t a2 = (uint32_t)__builtin_amdgcn_ds_bpermute(idx1, (int)u[2*mc][0]);
        uint32_t b2 = (uint32_t)__builtin_amdgcn_ds_bpermute(idx1, (int)u[2*mc+1][0]);
        uint32_t a3 = (uint32_t)__builtin_amdgcn_ds_bpermute(idx1, (int)u[2*mc][1]);
        uint32_t b3 = (uint32_t)__builtin_amdgcn_ds_bpermute(idx1, (int)u[2*mc+1][1]);
        bool hi = (lg >= 2);
        union { uint32_t w[4]; bf16x8 v; } pu;
        pu.w[0] = hi ? b0 : a0;
        pu.w[1] = hi ? b1 : a1;
        pu.w[2] = hi ? b2 : a2;
        pu.w[3] = hi ? b3 : a3;
        bf16x8 pa = pu.v;
        #pragma unroll
        for (int dt = 0; dt < 4; ++dt) {
          bf16x8 vf = *(const bf16x8*)(&Vt[dt*16 + lr][mc*32 + lg*8]);
          oacc[dt] = __builtin_amdgcn_mfma_f32_16x16x32_bf16(pa, vf, oacc[dt], 0, 0, 0);
        }
      }
    }

    // store compact: zsel[b*CAP + n][h*ND + d]
    #pragma unroll
    for (int r = 0; r < 4; ++r) {
      int nloc = qc*16 + 4*lg + r;
      if (nloc < cntb) {
        u16* op = zsel + qbase + (size_t)nloc * NC + lr;
        #pragma unroll
        for (int dt = 0; dt < 4; ++dt)
          op[dt*16] = f2bf(oacc[dt][r]);
      }
    }
  }
}

// ---------------- proj for selected rows: out[tok] = zsel @ Wp^T + bp -------
// grid: x = b*3 + rowchunk, y = col tile (6). f32 scatter into dense output.
__global__ __launch_bounds__(256) void proj_sel(const u16* __restrict__ zsel,
    const u16* __restrict__ wpb, float* __restrict__ out,
    const float* __restrict__ bp, const int* __restrict__ idx,
    const int* __restrict__ cnt) {
  alignas(16) __shared__ u16 As[32][32];
  alignas(16) __shared__ u16 Bs[128][32];
  int bx = blockIdx.x;
  int b = bx / 3, rc = bx % 3;
  int cntb = cnt[b];
  if (rc * 32 >= cntb) return;
  int n0 = blockIdx.y * 128;
  int tid = threadIdx.x, lane = tid & 63, wave = tid >> 6;

  int chA = wave * 64 + lane;
  const u16* baseA = zsel + (size_t)(b * CAP + rc * 32 + (chA >> 2)) * NC + (chA & 3) * 8;
  u16* ldsA = &As[0][0] + (size_t)(wave * 64) * 8;
  int chB0 = wave * 64 + lane, chB1 = 256 + wave * 64 + lane;
  const u16* baseB0 = wpb + (size_t)(n0 + (chB0 >> 2)) * NC + (chB0 & 3) * 8;
  const u16* baseB1 = wpb + (size_t)(n0 + (chB1 >> 2)) * NC + (chB1 & 3) * 8;
  u16* ldsB0 = &Bs[0][0] + (size_t)(wave * 64) * 8;
  u16* ldsB1 = &Bs[0][0] + (size_t)(256 + wave * 64) * 8;

  int lr = lane & 15, lg = lane >> 4, lk = lg * 8;
  int wc = wave * 32;
  f32x4 acc[2][2];
  #pragma unroll
  for (int i = 0; i < 2; ++i)
    #pragma unroll
    for (int j = 0; j < 2; ++j) acc[i][j] = (f32x4){0.f,0.f,0.f,0.f};

  for (int k0 = 0; k0 < NC; k0 += 32) {
    if (wave < 2) gl_lds16(baseA + k0, ldsA);
    gl_lds16(baseB0 + k0, ldsB0);
    gl_lds16(baseB1 + k0, ldsB1);
    __syncthreads();
    bf16x8 af[2], bfr[2];
    #pragma unroll
    for (int f = 0; f < 2; ++f) {
      af[f]  = *(const bf16x8*)(&As[f*16 + lr][lk]);
      bfr[f] = *(const bf16x8*)(&Bs[wc + f*16 + lr][lk]);
    }
    #pragma unroll
    for (int i = 0; i < 2; ++i)
      #pragma unroll
      for (int j = 0; j < 2; ++j)
        acc[i][j] = __builtin_amdgcn_mfma_f32_16x16x32_bf16(af[i], bfr[j], acc[i][j], 0, 0, 0);
    __syncthreads();
  }

  #pragma unroll
  for (int i = 0; i < 2; ++i)
    #pragma unroll
    for (int j = 0; j < 2; ++j)
      #pragma unroll
      for (int r = 0; r < 4; ++r) {
        int rsel = rc*32 + i*16 + 4*lg + r;
        if (rsel < cntb) {
          int tok = idx[b * CAP + rsel];
          int col = n0 + wc + j*16 + lr;
          out[(size_t)(b * NN + tok) * NC + col] = acc[i][j][r] + bp[col];
        }
      }
}

// ---------------- dense NT GEMM (round-3 proven): 128x128, BK=32, linear ----
// out[m][n] = sum_k A[m][k]*W[n][k]
template<int F32OUT>
__global__ __launch_bounds__(256) void gemm_nt(const u16* __restrict__ A,
                                               const u16* __restrict__ W,
                                               u16* __restrict__ obf,
                                               float* __restrict__ of32,
                                               const float* __restrict__ bias,
                                               int M) {
  alignas(16) __shared__ u16 As[128][32];
  alignas(16) __shared__ u16 Bs[128][32];
  int m0 = blockIdx.x * 128;
  int n0 = blockIdx.y * 128;
  int tid = threadIdx.x;
  int lane = tid & 63, wave = tid >> 6;
  int wr = (wave >> 1) * 64, wc = (wave & 1) * 64;
  int lr = lane & 15;
  int lk = (lane >> 4) * 8;

  f32x4 acc[4][4];
  #pragma unroll
  for (int i = 0; i < 4; ++i)
    #pragma unroll
    for (int j = 0; j < 4; ++j)
      acc[i][j] = (f32x4){0.f, 0.f, 0.f, 0.f};

  for (int k0 = 0; k0 < NC; k0 += 32) {
    #pragma unroll
    for (int i = 0; i < 2; ++i) {
      int c = wave * 2 + i;
      int id = c * 64 + lane;
      int row = id >> 2, col8 = (id & 3) * 8;
      gl_lds16(A + (size_t)(m0 + row) * NC + k0 + col8, &As[0][0] + c * 512);
      gl_lds16(W + (size_t)(n0 + row) * NC + k0 + col8, &Bs[0][0] + c * 512);
    }
    __syncthreads();
    bf16x8 af[4], bfr[4];
    #pragma unroll
    for (int f = 0; f < 4; ++f) {
      af[f]  = *(const bf16x8*)(&As[wr + f*16 + lr][lk]);
      bfr[f] = *(const bf16x8*)(&Bs[wc + f*16 + lr][lk]);
    }
    #pragma unroll
    for (int i = 0; i < 4; ++i)
      #pragma unroll
      for (int j = 0; j < 4; ++j)
        acc[i][j] = __builtin_amdgcn_mfma_f32_16x16x32_bf16(af[i], bfr[j], acc[i][j], 0, 0, 0);
    __syncthreads();
  }

  int lg = lane >> 4;
  #pragma unroll
  for (int i = 0; i < 4; ++i) {
    int rbase = m0 + wr + i*16 + 4*lg;
    #pragma unroll
    for (int j = 0; j < 4; ++j) {
      int col = n0 + wc + j*16 + lr;
      #pragma unroll
      for (int r = 0; r < 4; ++r) {
        int row = rbase + r;
        if (row < M) {
          if (F32OUT) of32[(size_t)row * NC + col] = acc[i][j][r] + bias[col];
          else        obf[(size_t)row * NC + col] = f2bf(acc[i][j][r]);
        }
      }
    }
  }
}

// ---------------------------------------------------------------------------
extern "C" void kernel_launch(void* const* d_in, const int* in_sizes, int n_in,
                              void* d_out, int out_size, void* d_ws, size_t ws_size,
                              hipStream_t stream) {
  const float* x  = (const float*)d_in[0];
  const float* g1 = (const float*)d_in[1];
  const float* g2 = (const float*)d_in[2];
  const float* Wq = (const float*)d_in[3];
  const float* Wk = (const float*)d_in[4];
  const float* Wv = (const float*)d_in[5];
  const float* Wp = (const float*)d_in[6];
  const float* bp = (const float*)d_in[7];
  const float* Wm = (const float*)d_in[8];
  const float* bm = (const float*)d_in[9];
  float* out = (float*)d_out;

  const size_t act_sz = ASZ * 2;
  const size_t w_sz   = WSZ * 2;
  const size_t sel_sz = SELSZ * 2;
  size_t need = act_sz + 4*sel_sz + 6*w_sz + (size_t)NM*4 + (size_t)NB*CAP*4 + 256;
  if (ws_size < need) return;

  char* p = (char*)d_ws;
  u16* xb   = (u16*)p; p += act_sz;
  u16* qsel = (u16*)p; p += sel_sz;    // qsel,ksel,vsel consecutive (z*SELSZ)
  u16* ksel = (u16*)p; p += sel_sz;
  u16* vsel = (u16*)p; p += sel_sz;
  u16* zsel = (u16*)p; p += sel_sz;
  u16* wqb  = (u16*)p; p += w_sz;      // wqb,wkb,wvb consecutive (z*WSZ)
  u16* wkb  = (u16*)p; p += w_sz;
  u16* wvb  = (u16*)p; p += w_sz;
  u16* wpb  = (u16*)p; p += w_sz;
  u16* wvtb = (u16*)p; p += w_sz;      // Wv^T bf16
  u16* wvpb = (u16*)p; p += w_sz;      // Wvp = Wp @ Wv (row i, col k layout)
  float* ts = (float*)p; p += (size_t)NM*4;
  int* idx  = (int*)p;  p += (size_t)NB*CAP*4;
  int* cnt  = (int*)p;
  (void)ksel; (void)vsel; (void)wkb; (void)wvb;

  // 1. conversions + Wv transpose
  cvt_all<<<dim3(XBLK + 4*WBLK), 256, 0, stream>>>(
      x, Wq, Wk, Wv, Wp, xb, wqb, wkb, wvb, wpb);
  trans_wv<<<dim3(144), 256, 0, stream>>>(Wv, wvtb);

  // 2. gates + compact
  gate_kernel<<<dim3(NM/4), 256, 0, stream>>>(x, g1, g2, Wm, bm, ts);
  compact_kernel<<<dim3(NB), 256, 0, stream>>>(ts, idx, cnt);

  // 3. Wvp = Wp @ Wv  (as NT: Wvp[i][k] = sum_j Wpb[i][j] * WvT[k][j])
  gemm_nt<0><<<dim3(6, 6), 256, 0, stream>>>(wpb, wvtb, wvpb, nullptr, nullptr, NC);

  // 4. Q/K/V projections for selected rows only
  gemm_sel<<<dim3(NB*3, 6, 3), 256, 0, stream>>>(xb, wqb, qsel, idx, cnt);

  // 5. sparse attention -> compacted zsel
  attn_sel<<<dim3(NB*NH), 256, 0, stream>>>(qsel, ksel, vsel, zsel, cnt);

  // 6. dense fused GEMM: out = x @ Wvp^T + bp (default/unselected path)
  gemm_nt<1><<<dim3((NM + 127)/128, NC/128), 256, 0, stream>>>(
      xb, wvpb, nullptr, out, bp, NM);

  // 7. overwrite selected rows: out[tok] = zsel @ Wp^T + bp
  proj_sel<<<dim3(NB*3, 6), 256, 0, stream>>>(zsel, wpb, out, bp, idx, cnt);
}

// Round 6
// 115.947 us; speedup vs baseline: 1.2694x; 1.1697x over previous
//
#include <hip/hip_runtime.h>
#include <hip/hip_bf16.h>
#include <cstdint>

typedef unsigned short u16;
typedef __attribute__((ext_vector_type(8))) short bf16x8;
typedef __attribute__((ext_vector_type(4))) float f32x4;

#define NB 64
#define NN 197
#define NC 768
#define NH 12
#define ND 64
#define NM (NB*NN)   // 12608
#define CAP 96       // max selected tokens per batch (mean ~26)
#define ASZ ((size_t)NM*NC)
#define WSZ ((size_t)NC*NC)
#define SELSZ ((size_t)NB*CAP*NC)

__device__ __forceinline__ u16 f2bf(float f) {
  uint32_t u = __float_as_uint(f);
  u += 0x7fffu + ((u >> 16) & 1u);
  return (u16)(u >> 16);
}

__device__ __forceinline__ void gl_lds16(const u16* g, u16* l) {
  __builtin_amdgcn_global_load_lds(
      (const __attribute__((address_space(1))) void*)g,
      (__attribute__((address_space(3))) void*)l, 16, 0, 0);
}

// self-compact: rebuild per-batch ordered selected-token list from ts in LDS.
// All 256 threads must enter. 2 __syncthreads. Returns capped count.
__device__ __forceinline__ int self_compact(const float* __restrict__ ts, int b,
                                            int* sidx, unsigned long long* bmask) {
  int t = threadIdx.x, lane = t & 63, wave = t >> 6;
  bool sel = (t < NN) && (ts[b * NN + t] > 0.5f);
  unsigned long long m = __ballot(sel);
  if (lane == 0) bmask[wave] = m;
  for (int i = t; i < CAP; i += 256) sidx[i] = 0;   // pad -> token 0
  __syncthreads();
  int before = 0, total = 0;
  #pragma unroll
  for (int w = 0; w < 4; ++w) {
    int c = __popcll(bmask[w]);
    total += c;
    if (w < wave) before += c;
  }
  int within = __popcll(bmask[wave] & ((lane == 0) ? 0ull : (~0ull >> (64 - lane))));
  int pos = before + within;
  int cntc = total < CAP ? total : CAP;
  if (sel && pos < CAP) sidx[pos] = t;
  __syncthreads();
  return cntc;
}

// ===================== K1: gate | cvt x | cvt weights | trans Wv ============
#define GATEB 3152   // NM/4
#define XBLK 9456    // ASZ/4/256 (exact)
#define WBLK 576     // WSZ/4/256 (exact)
#define TRBLK 144
// grid = GATEB + XBLK + 4*WBLK + TRBLK = 15056
__global__ __launch_bounds__(256) void k1_prep(const float* __restrict__ x,
    const float* __restrict__ g1, const float* __restrict__ g2,
    const float* __restrict__ Wm, const float* __restrict__ bm,
    const float* __restrict__ wq, const float* __restrict__ wk,
    const float* __restrict__ wv, const float* __restrict__ wp,
    u16* __restrict__ xb, u16* __restrict__ wqb, u16* __restrict__ wkb,
    u16* __restrict__ wvb, u16* __restrict__ wpb, u16* __restrict__ wvt,
    float* __restrict__ ts) {
  __shared__ u16 T[64][72];
  int bid = blockIdx.x, tid = threadIdx.x;

  if (bid < GATEB) {                       // ---- gate: 1 token per wave
    int wave = tid >> 6, lane = tid & 63;
    int wid = bid * 4 + wave;
    int b = wid / NN, n = wid % NN;
    float o = 1.0f;
    if (n != 0) {
      const float* xr = x + (size_t)wid * NC;
      double acc = 0.0;
      #pragma unroll
      for (int i = 0; i < 12; ++i)
        acc += (double)xr[lane + 64*i] * (double)Wm[lane + 64*i];
      #pragma unroll
      for (int off = 32; off; off >>= 1) acc += __shfl_down(acc, off);
      double z = (acc + (double)bm[0] + (double)g1[b*(NN-1) + n - 1]
                                      - (double)g2[b*(NN-1) + n - 1]) / 5.0;
      o = (z > 0.4054651081081643820) ? 1.0f : 0.0f;  // sigmoid(z)>0.6
      o = __shfl(o, 0);
    }
    if (lane == 0) ts[wid] = o;
    return;
  }
  bid -= GATEB;
  if (bid < XBLK) {                        // ---- cvt x -> xb
    int i = bid * 256 + tid;
    float4 f = ((const float4*)x)[i];
    ushort4 o;
    o.x = f2bf(f.x); o.y = f2bf(f.y); o.z = f2bf(f.z); o.w = f2bf(f.w);
    ((ushort4*)xb)[i] = o;
    return;
  }
  bid -= XBLK;
  if (bid < 4*WBLK) {                      // ---- cvt weights
    int seg = bid / WBLK;
    int i = (bid - seg * WBLK) * 256 + tid;
    const float* src; u16* dst;
    if (seg == 0)      { src = wq; dst = wqb; }
    else if (seg == 1) { src = wk; dst = wkb; }
    else if (seg == 2) { src = wv; dst = wvb; }
    else               { src = wp; dst = wpb; }
    float4 f = ((const float4*)src)[i];
    ushort4 o;
    o.x = f2bf(f.x); o.y = f2bf(f.y); o.z = f2bf(f.z); o.w = f2bf(f.w);
    ((ushort4*)dst)[i] = o;
    return;
  }
  bid -= 4*WBLK;                           // ---- transpose Wv -> wvt (bf16)
  {
    int bx = bid % 12, by = bid / 12;
    int j0 = by * 64, k0 = bx * 64;
    #pragma unroll
    for (int g = 0; g < 4; ++g) {
      int r = g * 16 + (tid >> 4);
      int c4 = (tid & 15) * 4;
      float4 f = *(const float4*)(wv + (size_t)(j0 + r) * NC + k0 + c4);
      T[c4 + 0][r] = f2bf(f.x);
      T[c4 + 1][r] = f2bf(f.y);
      T[c4 + 2][r] = f2bf(f.z);
      T[c4 + 3][r] = f2bf(f.w);
    }
    __syncthreads();
    #pragma unroll
    for (int g = 0; g < 4; ++g) {
      int r = g * 16 + (tid >> 4);
      int c4 = (tid & 15) * 4;
      ushort4 o = *(ushort4*)&T[r][c4];
      *(ushort4*)(wvt + (size_t)(k0 + r) * NC + j0 + c4) = o;
    }
  }
}

// ===================== K2: Wvp GEMM (36) | gemm_sel QKV (3456) ==============
// grid = 36 + 192*18 = 3492
__global__ __launch_bounds__(256) void k2_wvp_qkv(const u16* __restrict__ xb,
    const u16* __restrict__ wq3, const u16* __restrict__ wpb,
    const u16* __restrict__ wvt, u16* __restrict__ wvpb,
    u16* __restrict__ sel3, const float* __restrict__ ts) {
  alignas(16) __shared__ u16 SA[128][32];
  alignas(16) __shared__ u16 SB[128][32];
  __shared__ int sidx[CAP];
  __shared__ unsigned long long bmask[4];
  int bid = blockIdx.x;
  int tid = threadIdx.x, lane = tid & 63, wave = tid >> 6;
  int lr = lane & 15, lg = lane >> 4, lk = lg * 8;

  if (bid < 36) {
    // ---- Wvp[i][k] = sum_j Wp[i][j]*Wv[j][k]  (NT vs wvt), 128x128 tile
    int m0 = (bid / 6) * 128, n0 = (bid % 6) * 128;
    int wr = (wave >> 1) * 64, wc = (wave & 1) * 64;
    f32x4 acc[4][4];
    #pragma unroll
    for (int i = 0; i < 4; ++i)
      #pragma unroll
      for (int j = 0; j < 4; ++j) acc[i][j] = (f32x4){0.f,0.f,0.f,0.f};
    for (int k0 = 0; k0 < NC; k0 += 32) {
      #pragma unroll
      for (int i = 0; i < 2; ++i) {
        int c = wave * 2 + i;
        int id = c * 64 + lane;
        int row = id >> 2, col8 = (id & 3) * 8;
        gl_lds16(wpb + (size_t)(m0 + row) * NC + k0 + col8, &SA[0][0] + c * 512);
        gl_lds16(wvt + (size_t)(n0 + row) * NC + k0 + col8, &SB[0][0] + c * 512);
      }
      __syncthreads();
      bf16x8 af[4], bfr[4];
      #pragma unroll
      for (int f = 0; f < 4; ++f) {
        af[f]  = *(const bf16x8*)(&SA[wr + f*16 + lr][lk]);
        bfr[f] = *(const bf16x8*)(&SB[wc + f*16 + lr][lk]);
      }
      #pragma unroll
      for (int i = 0; i < 4; ++i)
        #pragma unroll
        for (int j = 0; j < 4; ++j)
          acc[i][j] = __builtin_amdgcn_mfma_f32_16x16x32_bf16(af[i], bfr[j], acc[i][j], 0, 0, 0);
      __syncthreads();
    }
    #pragma unroll
    for (int i = 0; i < 4; ++i)
      #pragma unroll
      for (int j = 0; j < 4; ++j)
        #pragma unroll
        for (int r = 0; r < 4; ++r)
          wvpb[(size_t)(m0 + wr + i*16 + 4*lg + r) * NC + n0 + wc + j*16 + lr] =
              f2bf(acc[i][j][r]);
    return;
  }

  // ---- gemm_sel: compacted Q/K/V projection, 32x128 tile
  int t = bid - 36;
  int gb = t / 18, r18 = t % 18;
  int y = r18 / 3, z = r18 % 3;
  int b = gb / 3, rc = gb % 3;
  int cntb = self_compact(ts, b, sidx, bmask);
  if (rc * 32 >= cntb) return;
  const u16* W = wq3 + (size_t)z * WSZ;
  u16* o = sel3 + (size_t)z * SELSZ;
  int n0 = y * 128;

  int chA = wave * 64 + lane;
  int tokA = sidx[rc * 32 + (chA >> 2)];
  const u16* baseA = xb + (size_t)(b * NN + tokA) * NC + (chA & 3) * 8;
  u16* ldsA = &SA[0][0] + (size_t)(wave * 64) * 8;
  int chB0 = wave * 64 + lane, chB1 = 256 + wave * 64 + lane;
  const u16* baseB0 = W + (size_t)(n0 + (chB0 >> 2)) * NC + (chB0 & 3) * 8;
  const u16* baseB1 = W + (size_t)(n0 + (chB1 >> 2)) * NC + (chB1 & 3) * 8;
  u16* ldsB0 = &SB[0][0] + (size_t)(wave * 64) * 8;
  u16* ldsB1 = &SB[0][0] + (size_t)(256 + wave * 64) * 8;

  int wc = wave * 32;
  f32x4 acc[2][2];
  #pragma unroll
  for (int i = 0; i < 2; ++i)
    #pragma unroll
    for (int j = 0; j < 2; ++j) acc[i][j] = (f32x4){0.f,0.f,0.f,0.f};

  for (int k0 = 0; k0 < NC; k0 += 32) {
    if (wave < 2) gl_lds16(baseA + k0, ldsA);
    gl_lds16(baseB0 + k0, ldsB0);
    gl_lds16(baseB1 + k0, ldsB1);
    __syncthreads();
    bf16x8 af[2], bfr[2];
    #pragma unroll
    for (int f = 0; f < 2; ++f) {
      af[f]  = *(const bf16x8*)(&SA[f*16 + lr][lk]);
      bfr[f] = *(const bf16x8*)(&SB[wc + f*16 + lr][lk]);
    }
    #pragma unroll
    for (int i = 0; i < 2; ++i)
      #pragma unroll
      for (int j = 0; j < 2; ++j)
        acc[i][j] = __builtin_amdgcn_mfma_f32_16x16x32_bf16(af[i], bfr[j], acc[i][j], 0, 0, 0);
    __syncthreads();
  }

  #pragma unroll
  for (int i = 0; i < 2; ++i)
    #pragma unroll
    for (int j = 0; j < 2; ++j)
      #pragma unroll
      for (int r = 0; r < 4; ++r) {
        int rsel = rc*32 + i*16 + 4*lg + r;
        if (rsel < cntb)
          o[(size_t)(b * CAP + rsel) * NC + n0 + wc + j*16 + lr] = f2bf(acc[i][j][r]);
      }
}

// ===================== K3: sparse attention per (b,h) =======================
__global__ __launch_bounds__(256) void attn_sel(const u16* __restrict__ qsel,
    const u16* __restrict__ ksel, const u16* __restrict__ vsel,
    u16* __restrict__ zsel, const float* __restrict__ ts) {
  alignas(16) __shared__ u16 Vt[64][232];
  __shared__ unsigned long long bmask[4];
  int bh = blockIdx.x;
  int b = bh / NH, h = bh % NH;
  int tid = threadIdx.x, lane = tid & 63, wave = tid >> 6;
  int lr = lane & 15, lg = lane >> 4;
  const size_t qbase = (size_t)b * CAP * NC + (size_t)h * ND;

  // self-count
  bool selt = (tid < NN) && (ts[b * NN + tid] > 0.5f);
  unsigned long long m = __ballot(selt);
  if (lane == 0) bmask[wave] = m;
  __syncthreads();
  int cntb = 0;
  #pragma unroll
  for (int w = 0; w < 4; ++w) cntb += __popcll(bmask[w]);
  if (cntb > CAP) cntb = CAP;

  // stage V^T from compacted vsel
  for (int id = tid; id < cntb * 8; id += 256) {
    int i = id >> 3, c8 = (id & 7) * 8;
    int4 val = *(const int4*)(vsel + qbase + (size_t)i * NC + c8);
    u16 tmp[8];
    *(int4*)tmp = val;
    #pragma unroll
    for (int e = 0; e < 8; ++e) Vt[c8 + e][i] = tmp[e];
  }
  for (int id = tid; id < 64 * 32; id += 256)
    Vt[id >> 5][cntb + (id & 31)] = 0;
  __syncthreads();

  int nchunk = (cntb + 15) >> 4;
  int mtmax  = nchunk;
  int mcmax  = (cntb + 31) >> 5;
  int idx0 = (((lane & 15) | ((lane & 16) << 1))) << 2;
  int idx1 = idx0 + 64;

  for (int qc = wave; qc < nchunk; qc += 4) {
    const u16* qp = qsel + qbase + (size_t)(qc * 16 + lr) * NC + lg * 8;
    bf16x8 qf0 = *(const bf16x8*)(qp);
    bf16x8 qf1 = *(const bf16x8*)(qp + 32);

    f32x4 s[6];
    #pragma unroll
    for (int mt = 0; mt < 6; ++mt) s[mt] = (f32x4){0.f,0.f,0.f,0.f};
    #pragma unroll
    for (int mt = 0; mt < 6; ++mt) {
      if (mt < mtmax) {
        const u16* kp = ksel + qbase + (size_t)(mt * 16 + lr) * NC + lg * 8;
        bf16x8 kf0 = *(const bf16x8*)(kp);
        bf16x8 kf1 = *(const bf16x8*)(kp + 32);
        f32x4 a = (f32x4){0.f,0.f,0.f,0.f};
        a = __builtin_amdgcn_mfma_f32_16x16x32_bf16(kf0, qf0, a, 0, 0, 0);
        a = __builtin_amdgcn_mfma_f32_16x16x32_bf16(kf1, qf1, a, 0, 0, 0);
        s[mt] = a;
      }
    }

    float mx = -3e38f;
    #pragma unroll
    for (int mt = 0; mt < 6; ++mt)
      #pragma unroll
      for (int jj = 0; jj < 4; ++jj) {
        int mm = mt*16 + 4*lg + jj;
        float val = (mm < cntb) ? s[mt][jj] * 0.125f : -1e30f;
        s[mt][jj] = val;
        mx = fmaxf(mx, val);
      }
    mx = fmaxf(mx, __shfl_xor(mx, 16));
    mx = fmaxf(mx, __shfl_xor(mx, 32));
    float sum = 0.f;
    #pragma unroll
    for (int mt = 0; mt < 6; ++mt)
      #pragma unroll
      for (int jj = 0; jj < 4; ++jj) {
        float pv = __expf(s[mt][jj] - mx);
        s[mt][jj] = pv;
        sum += pv;
      }
    sum += __shfl_xor(sum, 16);
    sum += __shfl_xor(sum, 32);
    float inv = 1.0f / sum;

    uint32_t u[6][2];
    #pragma unroll
    for (int mt = 0; mt < 6; ++mt) {
      u[mt][0] = ((uint32_t)f2bf(s[mt][1]*inv) << 16) | f2bf(s[mt][0]*inv);
      u[mt][1] = ((uint32_t)f2bf(s[mt][3]*inv) << 16) | f2bf(s[mt][2]*inv);
    }

    f32x4 oacc[4];
    #pragma unroll
    for (int dt = 0; dt < 4; ++dt) oacc[dt] = (f32x4){0.f,0.f,0.f,0.f};
    #pragma unroll
    for (int mc = 0; mc < 3; ++mc) {
      if (mc < mcmax) {
        uint32_t a0 = (uint32_t)__builtin_amdgcn_ds_bpermute(idx0, (int)u[2*mc][0]);
        uint32_t b0 = (uint32_t)__builtin_amdgcn_ds_bpermute(idx0, (int)u[2*mc+1][0]);
        uint32_t a1 = (uint32_t)__builtin_amdgcn_ds_bpermute(idx0, (int)u[2*mc][1]);
        uint32_t b1 = (uint32_t)__builtin_amdgcn_ds_bpermute(idx0, (int)u[2*mc+1][1]);
        uint32_t a2 = (uint32_t)__builtin_amdgcn_ds_bpermute(idx1, (int)u[2*mc][0]);
        uint32_t b2 = (uint32_t)__builtin_amdgcn_ds_bpermute(idx1, (int)u[2*mc+1][0]);
        uint32_t a3 = (uint32_t)__builtin_amdgcn_ds_bpermute(idx1, (int)u[2*mc][1]);
        uint32_t b3 = (uint32_t)__builtin_amdgcn_ds_bpermute(idx1, (int)u[2*mc+1][1]);
        bool hi = (lg >= 2);
        union { uint32_t w[4]; bf16x8 v; } pu;
        pu.w[0] = hi ? b0 : a0;
        pu.w[1] = hi ? b1 : a1;
        pu.w[2] = hi ? b2 : a2;
        pu.w[3] = hi ? b3 : a3;
        bf16x8 pa = pu.v;
        #pragma unroll
        for (int dt = 0; dt < 4; ++dt) {
          bf16x8 vf = *(const bf16x8*)(&Vt[dt*16 + lr][mc*32 + lg*8]);
          oacc[dt] = __builtin_amdgcn_mfma_f32_16x16x32_bf16(pa, vf, oacc[dt], 0, 0, 0);
        }
      }
    }

    #pragma unroll
    for (int r = 0; r < 4; ++r) {
      int nloc = qc*16 + 4*lg + r;
      if (nloc < cntb) {
        u16* op = zsel + qbase + (size_t)nloc * NC + lr;
        #pragma unroll
        for (int dt = 0; dt < 4; ++dt)
          op[dt*16] = f2bf(oacc[dt][r]);
      }
    }
  }
}

// ===================== K4: dense fused GEMM (594) | proj_sel (1152) =========
#define DBLK 594   // 99 m-tiles x 6 n-tiles
// grid = 594 + 192*6 = 1746
__global__ __launch_bounds__(256) void k4_out(const u16* __restrict__ xb,
    const u16* __restrict__ wvpb, const u16* __restrict__ zsel,
    const u16* __restrict__ wpb, const float* __restrict__ ts,
    const float* __restrict__ bp, float* __restrict__ out) {
  alignas(16) __shared__ u16 SA[128][32];
  alignas(16) __shared__ u16 SB[128][32];
  __shared__ int sidx[CAP];
  __shared__ unsigned long long bmask[4];
  int bid = blockIdx.x;
  int tid = threadIdx.x, lane = tid & 63, wave = tid >> 6;
  int lr = lane & 15, lg = lane >> 4, lk = lg * 8;

  if (bid < DBLK) {
    // ---- dense: out[row] = x @ Wvp^T + bp for UNSELECTED rows
    int m0 = (bid / 6) * 128, n0 = (bid % 6) * 128;
    int wr = (wave >> 1) * 64, wc = (wave & 1) * 64;
    f32x4 acc[4][4];
    #pragma unroll
    for (int i = 0; i < 4; ++i)
      #pragma unroll
      for (int j = 0; j < 4; ++j) acc[i][j] = (f32x4){0.f,0.f,0.f,0.f};
    for (int k0 = 0; k0 < NC; k0 += 32) {
      #pragma unroll
      for (int i = 0; i < 2; ++i) {
        int c = wave * 2 + i;
        int id = c * 64 + lane;
        int row = id >> 2, col8 = (id & 3) * 8;
        gl_lds16(xb + (size_t)(m0 + row) * NC + k0 + col8, &SA[0][0] + c * 512);
        gl_lds16(wvpb + (size_t)(n0 + row) * NC + k0 + col8, &SB[0][0] + c * 512);
      }
      __syncthreads();
      bf16x8 af[4], bfr[4];
      #pragma unroll
      for (int f = 0; f < 4; ++f) {
        af[f]  = *(const bf16x8*)(&SA[wr + f*16 + lr][lk]);
        bfr[f] = *(const bf16x8*)(&SB[wc + f*16 + lr][lk]);
      }
      #pragma unroll
      for (int i = 0; i < 4; ++i)
        #pragma unroll
        for (int j = 0; j < 4; ++j)
          acc[i][j] = __builtin_amdgcn_mfma_f32_16x16x32_bf16(af[i], bfr[j], acc[i][j], 0, 0, 0);
      __syncthreads();
    }
    #pragma unroll
    for (int i = 0; i < 4; ++i) {
      int rbase = m0 + wr + i*16 + 4*lg;
      #pragma unroll
      for (int j = 0; j < 4; ++j) {
        int col = n0 + wc + j*16 + lr;
        #pragma unroll
        for (int r = 0; r < 4; ++r) {
          int row = rbase + r;
          if (row < NM && ts[row] < 0.5f)
            out[(size_t)row * NC + col] = acc[i][j][r] + bp[col];
        }
      }
    }
    return;
  }

  // ---- proj_sel: out[tok] = zsel @ Wp^T + bp for SELECTED rows
  int t = bid - DBLK;
  int gb = t / 6, y = t % 6;
  int b = gb / 3, rc = gb % 3;
  int cntb = self_compact(ts, b, sidx, bmask);
  if (rc * 32 >= cntb) return;
  int n0 = y * 128;

  int chA = wave * 64 + lane;
  const u16* baseA = zsel + (size_t)(b * CAP + rc * 32 + (chA >> 2)) * NC + (chA & 3) * 8;
  u16* ldsA = &SA[0][0] + (size_t)(wave * 64) * 8;
  int chB0 = wave * 64 + lane, chB1 = 256 + wave * 64 + lane;
  const u16* baseB0 = wpb + (size_t)(n0 + (chB0 >> 2)) * NC + (chB0 & 3) * 8;
  const u16* baseB1 = wpb + (size_t)(n0 + (chB1 >> 2)) * NC + (chB1 & 3) * 8;
  u16* ldsB0 = &SB[0][0] + (size_t)(wave * 64) * 8;
  u16* ldsB1 = &SB[0][0] + (size_t)(256 + wave * 64) * 8;

  int wc = wave * 32;
  f32x4 acc[2][2];
  #pragma unroll
  for (int i = 0; i < 2; ++i)
    #pragma unroll
    for (int j = 0; j < 2; ++j) acc[i][j] = (f32x4){0.f,0.f,0.f,0.f};

  for (int k0 = 0; k0 < NC; k0 += 32) {
    if (wave < 2) gl_lds16(baseA + k0, ldsA);
    gl_lds16(baseB0 + k0, ldsB0);
    gl_lds16(baseB1 + k0, ldsB1);
    __syncthreads();
    bf16x8 af[2], bfr[2];
    #pragma unroll
    for (int f = 0; f < 2; ++f) {
      af[f]  = *(const bf16x8*)(&SA[f*16 + lr][lk]);
      bfr[f] = *(const bf16x8*)(&SB[wc + f*16 + lr][lk]);
    }
    #pragma unroll
    for (int i = 0; i < 2; ++i)
      #pragma unroll
      for (int j = 0; j < 2; ++j)
        acc[i][j] = __builtin_amdgcn_mfma_f32_16x16x32_bf16(af[i], bfr[j], acc[i][j], 0, 0, 0);
    __syncthreads();
  }

  #pragma unroll
  for (int i = 0; i < 2; ++i)
    #pragma unroll
    for (int j = 0; j < 2; ++j)
      #pragma unroll
      for (int r = 0; r < 4; ++r) {
        int rsel = rc*32 + i*16 + 4*lg + r;
        if (rsel < cntb) {
          int tok = sidx[rsel];
          int col = n0 + wc + j*16 + lr;
          out[(size_t)(b * NN + tok) * NC + col] = acc[i][j][r] + bp[col];
        }
      }
}

// ---------------------------------------------------------------------------
extern "C" void kernel_launch(void* const* d_in, const int* in_sizes, int n_in,
                              void* d_out, int out_size, void* d_ws, size_t ws_size,
                              hipStream_t stream) {
  const float* x  = (const float*)d_in[0];
  const float* g1 = (const float*)d_in[1];
  const float* g2 = (const float*)d_in[2];
  const float* Wq = (const float*)d_in[3];
  const float* Wk = (const float*)d_in[4];
  const float* Wv = (const float*)d_in[5];
  const float* Wp = (const float*)d_in[6];
  const float* bp = (const float*)d_in[7];
  const float* Wm = (const float*)d_in[8];
  const float* bm = (const float*)d_in[9];
  float* out = (float*)d_out;

  const size_t act_sz = ASZ * 2;
  const size_t w_sz   = WSZ * 2;
  const size_t sel_sz = SELSZ * 2;
  size_t need = act_sz + 4*sel_sz + 6*w_sz + (size_t)NM*4 + 256;
  if (ws_size < need) return;

  char* p = (char*)d_ws;
  u16* xb   = (u16*)p; p += act_sz;
  u16* qsel = (u16*)p; p += sel_sz;    // qsel,ksel,vsel consecutive (z*SELSZ)
  u16* ksel = (u16*)p; p += sel_sz;
  u16* vsel = (u16*)p; p += sel_sz;
  u16* zsel = (u16*)p; p += sel_sz;
  u16* wqb  = (u16*)p; p += w_sz;      // wqb,wkb,wvb consecutive (z*WSZ)
  u16* wkb  = (u16*)p; p += w_sz;
  u16* wvb  = (u16*)p; p += w_sz;
  u16* wpb  = (u16*)p; p += w_sz;
  u16* wvtb = (u16*)p; p += w_sz;      // Wv^T bf16
  u16* wvpb = (u16*)p; p += w_sz;      // Wvp = Wp @ Wv
  float* ts = (float*)p;
  (void)wkb; (void)wvb;

  // K1: gate | cvt x | cvt weights | trans Wv
  k1_prep<<<dim3(GATEB + XBLK + 4*WBLK + TRBLK), 256, 0, stream>>>(
      x, g1, g2, Wm, bm, Wq, Wk, Wv, Wp,
      xb, wqb, wkb, wvb, wpb, wvtb, ts);

  // K2: Wvp GEMM | compacted Q/K/V projections (self-compacting)
  k2_wvp_qkv<<<dim3(36 + NB*3*18), 256, 0, stream>>>(
      xb, wqb, wpb, wvtb, wvpb, qsel, ts);

  // K3: sparse attention -> zsel
  attn_sel<<<dim3(NB*NH), 256, 0, stream>>>(qsel, ksel, vsel, zsel, ts);

  // K4: dense fused out (unselected) | proj_sel scatter (selected)
  k4_out<<<dim3(DBLK + NB*3*6), 256, 0, stream>>>(
      xb, wvpb, zsel, wpb, ts, bp, out);
}